// Round 1
// 62.047 us; speedup vs baseline: 1.0404x; 1.0404x over previous
//
#include <hip/hip_runtime.h>
#include <math.h>

// Problem shape (from reference setup_inputs): B=4, H=320, W=320.
#define B_ 4
#define H_ 320
#define W_ 320
#define N_TOTAL (B_ * H_ * W_)        // 409600
#define ROWS 5                        // image rows owned per block
#define HALO 4                        // staged halo rows above/below
#define RSTAGE (ROWS + 2 * HALO)      // 13 staged rows
#define GROUPS (RSTAGE * 5)           // 65 ballot groups (W = 320 = 5*64)
#define BLOCKS_PER_B (H_ / ROWS)      // 64
#define NBLK (B_ * BLOCKS_PER_B)      // 256 blocks -> exactly 1 block/CU
#define BLOCK 640                     // 10 waves: waves wv and wv+5 share image row r0+wv
#define NW (BLOCK / 64)               // 10
#define FLAG_BASE 0xC0DE0000u

// Exact fallback: outward Chebyshev-ring scan on global memory.
// Taken only when best2 > (HALO+1)^2 after the windowed scan — probability
// ~2^-49 per pixel at 50% seed density, but keeps the kernel exact for any input.
__device__ int fallback_ring_scan(const int* __restrict__ img, int h, int w) {
    int best2 = 0x7fffffff;
    if (img[h * W_ + w] > 0) return 0;
    for (int r = 1; r < H_ + W_; ++r) {
        int r2 = r * r;
        if (r2 >= best2) break;
        int hlo = h - r, hhi = h + r;
        int wlo = w - r, whi = w + r;
        int wl = wlo > 0 ? wlo : 0;
        int wr = whi < (W_ - 1) ? whi : (W_ - 1);
        if (hlo >= 0) {
            const int* rowp = img + hlo * W_;
            for (int ww = wl; ww <= wr; ++ww)
                if (rowp[ww] > 0) { int dw = ww - w; int d2 = r2 + dw * dw; best2 = d2 < best2 ? d2 : best2; }
        }
        if (hhi < H_) {
            const int* rowp = img + hhi * W_;
            for (int ww = wl; ww <= wr; ++ww)
                if (rowp[ww] > 0) { int dw = ww - w; int d2 = r2 + dw * dw; best2 = d2 < best2 ? d2 : best2; }
        }
        int hl = (hlo + 1) > 0 ? (hlo + 1) : 0;
        int hr = (hhi - 1) < (H_ - 1) ? (hhi - 1) : (H_ - 1);
        if (wlo >= 0) {
            for (int hh = hl; hh <= hr; ++hh)
                if (img[hh * W_ + wlo] > 0) { int dh = hh - h; int d2 = dh * dh + r2; best2 = d2 < best2 ? d2 : best2; }
        }
        if (whi < W_) {
            for (int hh = hl; hh <= hr; ++hh)
                if (img[hh * W_ + whi] > 0) { int dh = hh - h; int d2 = dh * dh + r2; best2 = d2 < best2 ? d2 : best2; }
        }
    }
    return best2;
}

// Nearest set bit (|dw| <= 32) to position w in a bit-row stored as u64 words
// with a 64-bit zero lead pad (bit of pixel w' lives at 64+w').
// Returns |dw| in [0,32], or 64 if the 64-bit window is empty.
__device__ __forceinline__ int nearest_dw(const unsigned long long* __restrict__ row, int w) {
    int s = w + 32;                    // window start bit = 64 + w - 32
    int word = s >> 6, sh = s & 63;
    unsigned long long lo = row[word];
    unsigned long long win = sh ? ((lo >> sh) | (row[word + 1] << (64 - sh))) : lo;
    // win bit j corresponds to dw = j - 32 (center bit 32 = dw 0)
    int dw = 64;
    unsigned long long rw = win >> 32;             // dw >= 0
    unsigned long long lw = win << 32;             // dw in [-32,-1]
    if (rw) dw = __builtin_ctzll(rw);
    if (lw) { int dl = __builtin_clzll(lw) + 1; if (dl < dw) dw = dl; }
    return dw;
}

// Single fused dispatch: bitmask-staged exact EDT + sigmoid + loss,
// block partials published with agent-scope atomics + release flags; block 0
// consumes all partials (spin-poll) and writes the scalar. No second kernel.
//
// Loss algebra (LAMBDA=1): mean(p*d) + mean(1-p) = 1 + mean(p*(d-1)) —
// single accumulator, half the reduction/partial traffic.
//
// Latency structure: ALL global loads (3 logits + up to 7 staging ints per
// thread) are issued back-to-back into registers before any dependent use,
// so the block pays ~1 memory round-trip instead of ~10 serialized ones.
//
// Deadlock-safe: producers never wait; only block 0 spins. 256 blocks x 10
// waves = 1 block/CU on all 256 CUs (capacity 32 waves/CU).
__global__ __launch_bounds__(BLOCK) void fused_edt_loss(
        const float* __restrict__ logits,
        const int* __restrict__ tgt,
        double* __restrict__ partial /* [NBLK] */,
        unsigned int* __restrict__ flags /* [NBLK] */,
        float* __restrict__ out) {
    // 8 u64 per staged row: word 0 = lead pad, words 1..5 = 320 bits, 6..7 = tail pad
    __shared__ unsigned long long smrow[RSTAGE][8];
    __shared__ double s1[NW];

    int bid = blockIdx.x;
    int b = bid / BLOCKS_PER_B;
    int g = bid - b * BLOCKS_PER_B;
    int r0 = g * ROWS;
    const int* __restrict__ img = tgt + b * (H_ * W_);
    int t = threadIdx.x;
    int wv = t >> 6, lane = t & 63;
    int half = (wv >= ROWS) ? 1 : 0;   // two waves per row: halves [0,160) and [160,320)
    int rr = wv - half * ROWS;         // owned image row within block
    int gh = r0 + rr;
    int wbase = half * 160;

    // ---- prefetch logits: 3 loads (j=2 half-masked later), clamped in-bounds ----
    const float* __restrict__ lrow = logits + (b * H_ + gh) * W_;
    float xs[3];
#pragma unroll
    for (int j = 0; j < 3; ++j) {
        int w = wbase + (j << 6) + lane;
        xs[j] = lrow[w < W_ ? w : W_ - 1];   // clamp: lanes masked off in compute
    }

    // ---- prefetch staging ints: wave wv covers ballot-groups gg = wv + 10*i ----
    // group gg -> staged row rr2 = gg/5, word wd = gg%5; 65 groups over 10 waves.
    int gr0 = r0 - HALO;
    int ngg = (wv < 5) ? 7 : 6;
    int vals[7];
#pragma unroll
    for (int i = 0; i < 7; ++i) {
        if (i < ngg) {
            int gg = wv + i * 10;
            int rr2 = gg / 5, wd = gg - rr2 * 5;
            int gr = gr0 + rr2;
            int grc = gr < 0 ? 0 : (gr >= H_ ? H_ - 1 : gr);  // clamped: branch-free load
            vals[i] = img[grc * W_ + (wd << 6) + lane];
        }
    }

    if (t < RSTAGE) { smrow[t][0] = 0; smrow[t][6] = 0; smrow[t][7] = 0; }

    // ---- build bitmasks via wave ballots (loads already in flight/registers) ----
#pragma unroll
    for (int i = 0; i < 7; ++i) {
        if (i < ngg) {
            int gg = wv + i * 10;
            int rr2 = gg / 5, wd = gg - rr2 * 5;
            int gr = gr0 + rr2;
            bool p = (gr >= 0) && (gr < H_) && (vals[i] > 0);
            unsigned long long m = __ballot(p);
            if (lane == 0) smrow[rr2][1 + wd] = m;
        }
    }
    __syncthreads();

    // ---- per-pixel EDT + loss: wave handles its 160-px half-row (2.5 px/lane) ----
    int sr = HALO + rr;
    double acc = 0.0;
#pragma unroll
    for (int j = 0; j < 3; ++j) {
        bool act = (j < 2) || (lane < 32);   // j=2 covers the last 32 px of the half
        if (act) {
            int w = wbase + (j << 6) + lane;
            int dw0 = nearest_dw(smrow[sr], w);
            int best2 = (dw0 < 64) ? dw0 * dw0 : 0x3fffffff;
            for (int dh = 1; dh <= HALO; ++dh) {
                int dh2 = dh * dh;
                if (dh2 >= best2) break;
                int du = nearest_dw(smrow[sr - dh], w);
                if (du < 64) { int c = dh2 + du * du; if (c < best2) best2 = c; }
                int dd = nearest_dw(smrow[sr + dh], w);
                if (dd < 64) { int c = dh2 + dd * dd; if (c < best2) best2 = c; }
            }
            // exact iff best2 <= (HALO+1)^2 (all needed dh examined, |dw|<=32 regime)
            if (best2 > (HALO + 1) * (HALO + 1)) best2 = fallback_ring_scan(img, gh, w);

            float dist = sqrtf((float)best2);   // integer-exact in fp32 (< 2^24)
            float x = xs[j];
            float p = 1.0f / (1.0f + expf(-x));
            acc += (double)(p * (dist - 1.0f));
        }
    }

    // wave(64) shuffle reduce, then cross-wave LDS reduce
#pragma unroll
    for (int off = 32; off > 0; off >>= 1) acc += __shfl_down(acc, off, 64);
    if (lane == 0) s1[wv] = acc;
    __syncthreads();

    if (bid != 0) {
        // Producer: publish partial with device-coherent store, then release flag.
        if (t == 0) {
            double a = 0.0;
#pragma unroll
            for (int i = 0; i < NW; ++i) a += s1[i];
            __hip_atomic_store(&partial[bid], a, __ATOMIC_RELAXED, __HIP_MEMORY_SCOPE_AGENT);
            __hip_atomic_store(&flags[bid], FLAG_BASE | (unsigned)bid,
                               __ATOMIC_RELEASE, __HIP_MEMORY_SCOPE_AGENT);
        }
        return;
    }

    // Consumer (block 0): keep own sum in a register, then gather everyone else's.
    double own = 0.0;
    if (t == 0) {
#pragma unroll
        for (int i = 0; i < NW; ++i) own += s1[i];
    }
    __syncthreads();   // orders own-read before s1 reuse below

    double a1 = 0.0;
    if (t >= 1 && t < NBLK) {          // threads 1..255 each own one producer
        unsigned want = FLAG_BASE | (unsigned)t;
        while (__hip_atomic_load(&flags[t], __ATOMIC_ACQUIRE, __HIP_MEMORY_SCOPE_AGENT) != want) {
            __builtin_amdgcn_s_sleep(1);
        }
        a1 = __hip_atomic_load(&partial[t], __ATOMIC_RELAXED, __HIP_MEMORY_SCOPE_AGENT);
    }
#pragma unroll
    for (int off = 32; off > 0; off >>= 1) a1 += __shfl_down(a1, off, 64);
    if (lane == 0) s1[wv] = a1;
    __syncthreads();
    if (t == 0) {
        double total = own;
#pragma unroll
        for (int i = 0; i < NW; ++i) total += s1[i];
        out[0] = (float)(1.0 + total / (double)N_TOTAL);
    }
}

extern "C" void kernel_launch(void* const* d_in, const int* in_sizes, int n_in,
                              void* d_out, int out_size, void* d_ws, size_t ws_size,
                              hipStream_t stream) {
    const float* logits = (const float*)d_in[0];
    const int* targets  = (const int*)d_in[1];
    float* out = (float*)d_out;
    // ws layout: partial doubles [NBLK] (2048 B), then u32 flags [NBLK] (1024 B).
    // Flags are matched against per-slot magic (FLAG_BASE|bid): the 0xAA
    // poison (or any stale/garbage word) can never alias a valid flag.
    double* partial = (double*)d_ws;
    unsigned int* flags = (unsigned int*)((char*)d_ws + (size_t)NBLK * sizeof(double));

    fused_edt_loss<<<NBLK, BLOCK, 0, stream>>>(logits, targets, partial, flags, out);
}

// Round 2
// 62.007 us; speedup vs baseline: 1.0411x; 1.0006x over previous
//
#include <hip/hip_runtime.h>
#include <math.h>

// Problem shape (from reference setup_inputs): B=4, H=320, W=320.
#define B_ 4
#define H_ 320
#define W_ 320
#define N_TOTAL (B_ * H_ * W_)        // 409600
#define ROWS 5                        // image rows owned per block
#define HALO 3                        // staged halo rows above/below (exactness via fallback)
#define RSTAGE (ROWS + 2 * HALO)      // 11 staged rows
#define GROUPS (RSTAGE * 5)           // 55 ballot groups (W = 320 = 5*64)
#define BLOCKS_PER_B (H_ / ROWS)      // 64
#define NBLK (B_ * BLOCKS_PER_B)      // 256 blocks -> exactly 1 block/CU
#define BLOCK 640                     // 10 waves: waves wv and wv+5 share image row r0+wv
#define NW (BLOCK / 64)               // 10
#define FLAG_BASE 0xC0DE0000u

// Exact fallback: outward Chebyshev-ring scan on global memory.
// Taken only when best2 > (HALO+1)^2 after the windowed scan — probability
// ~2^-47 per pixel at 50% seed density, but keeps the kernel exact for any input.
__device__ int fallback_ring_scan(const int* __restrict__ img, int h, int w) {
    int best2 = 0x7fffffff;
    if (img[h * W_ + w] > 0) return 0;
    for (int r = 1; r < H_ + W_; ++r) {
        int r2 = r * r;
        if (r2 >= best2) break;
        int hlo = h - r, hhi = h + r;
        int wlo = w - r, whi = w + r;
        int wl = wlo > 0 ? wlo : 0;
        int wr = whi < (W_ - 1) ? whi : (W_ - 1);
        if (hlo >= 0) {
            const int* rowp = img + hlo * W_;
            for (int ww = wl; ww <= wr; ++ww)
                if (rowp[ww] > 0) { int dw = ww - w; int d2 = r2 + dw * dw; best2 = d2 < best2 ? d2 : best2; }
        }
        if (hhi < H_) {
            const int* rowp = img + hhi * W_;
            for (int ww = wl; ww <= wr; ++ww)
                if (rowp[ww] > 0) { int dw = ww - w; int d2 = r2 + dw * dw; best2 = d2 < best2 ? d2 : best2; }
        }
        int hl = (hlo + 1) > 0 ? (hlo + 1) : 0;
        int hr = (hhi - 1) < (H_ - 1) ? (hhi - 1) : (H_ - 1);
        if (wlo >= 0) {
            for (int hh = hl; hh <= hr; ++hh)
                if (img[hh * W_ + wlo] > 0) { int dh = hh - h; int d2 = dh * dh + r2; best2 = d2 < best2 ? d2 : best2; }
        }
        if (whi < W_) {
            for (int hh = hl; hh <= hr; ++hh)
                if (img[hh * W_ + whi] > 0) { int dh = hh - h; int d2 = dh * dh + r2; best2 = d2 < best2 ? d2 : best2; }
        }
    }
    return best2;
}

// Nearest set bit (|dw| <= 32) to position w in a bit-row stored as u64 words
// with a 64-bit zero lead pad (bit of pixel w' lives at 64+w').
// Returns |dw| in [0,32], or 64 if the 64-bit window is empty.
__device__ __forceinline__ int nearest_dw(const unsigned long long* __restrict__ row, int w) {
    int s = w + 32;                    // window start bit = 64 + w - 32
    int word = s >> 6, sh = s & 63;
    unsigned long long lo = row[word];
    unsigned long long win = sh ? ((lo >> sh) | (row[word + 1] << (64 - sh))) : lo;
    // win bit j corresponds to dw = j - 32 (center bit 32 = dw 0)
    int dw = 64;
    unsigned long long rw = win >> 32;             // dw >= 0
    unsigned long long lw = win << 32;             // dw in [-32,-1]
    if (rw) dw = __builtin_ctzll(rw);
    if (lw) { int dl = __builtin_clzll(lw) + 1; if (dl < dw) dw = dl; }
    return dw;
}

// Single fused dispatch: bitmask-staged exact EDT + sigmoid + loss,
// block partials published with agent-scope atomics + release flags; block 0
// consumes all partials (spin-poll) and writes the scalar. No second kernel.
//
// Loss algebra (LAMBDA=1): mean(p*d) + mean(1-p) = 1 + mean(p*(d-1)).
//
// Latency structure: target-staging loads are issued FIRST (the ballot path
// waits only on them — vmcnt drains oldest-first), logits loads ride behind
// and complete under the mask build. One memory round-trip on the critical
// path before __syncthreads.
//
// Deadlock-safe: producers never wait; only block 0 spins. 256 blocks x 10
// waves = 1 block/CU on all 256 CUs (capacity 32 waves/CU).
__global__ __launch_bounds__(BLOCK) void fused_edt_loss(
        const float* __restrict__ logits,
        const int* __restrict__ tgt,
        double* __restrict__ partial /* [NBLK] */,
        unsigned int* __restrict__ flags /* [NBLK] */,
        float* __restrict__ out) {
    // 8 u64 per staged row: word 0 = lead pad, words 1..5 = 320 bits, 6..7 = tail pad
    __shared__ unsigned long long smrow[RSTAGE][8];
    __shared__ double s1[NW];

    int bid = blockIdx.x;
    int b = bid / BLOCKS_PER_B;
    int g = bid - b * BLOCKS_PER_B;
    int r0 = g * ROWS;
    const int* __restrict__ img = tgt + b * (H_ * W_);
    int t = threadIdx.x;
    int wv = t >> 6, lane = t & 63;
    int half = (wv >= ROWS) ? 1 : 0;   // two waves per row: halves [0,160) and [160,320)
    int rr = wv - half * ROWS;         // owned image row within block
    int gh = r0 + rr;
    int wbase = half * 160;

    // ---- prefetch staging ints FIRST: wave wv covers ballot-groups gg = wv + 10*i ----
    // group gg -> staged row rr2 = gg/5, word wd = gg%5; 55 groups over 10 waves.
    int gr0 = r0 - HALO;
    int ngg = (wv < 5) ? 6 : 5;
    int vals[6];
#pragma unroll
    for (int i = 0; i < 6; ++i) {
        if (i < ngg) {
            int gg = wv + i * 10;
            int rr2 = gg / 5, wd = gg - rr2 * 5;
            int gr = gr0 + rr2;
            int grc = gr < 0 ? 0 : (gr >= H_ ? H_ - 1 : gr);  // clamped: branch-free load
            vals[i] = img[grc * W_ + (wd << 6) + lane];
        }
    }

    // ---- prefetch logits behind the staging loads (consumed much later) ----
    const float* __restrict__ lrow = logits + (b * H_ + gh) * W_;
    float xs[3];
#pragma unroll
    for (int j = 0; j < 3; ++j) {
        int w = wbase + (j << 6) + lane;
        xs[j] = lrow[w < W_ ? w : W_ - 1];   // clamp: lanes masked off in compute
    }

    if (t < RSTAGE) { smrow[t][0] = 0; smrow[t][6] = 0; smrow[t][7] = 0; }

    // ---- build bitmasks via wave ballots (loads already in flight/registers) ----
#pragma unroll
    for (int i = 0; i < 6; ++i) {
        if (i < ngg) {
            int gg = wv + i * 10;
            int rr2 = gg / 5, wd = gg - rr2 * 5;
            int gr = gr0 + rr2;
            bool p = (gr >= 0) && (gr < H_) && (vals[i] > 0);
            unsigned long long m = __ballot(p);
            if (lane == 0) smrow[rr2][1 + wd] = m;
        }
    }
    __syncthreads();

    // ---- per-pixel EDT + loss: wave handles its 160-px half-row (2.5 px/lane) ----
    int sr = HALO + rr;
    double acc = 0.0;
#pragma unroll
    for (int j = 0; j < 3; ++j) {
        bool act = (j < 2) || (lane < 32);   // j=2 covers the last 32 px of the half
        if (act) {
            int w = wbase + (j << 6) + lane;
            int dw0 = nearest_dw(smrow[sr], w);
            int best2 = (dw0 < 64) ? dw0 * dw0 : 0x3fffffff;
            for (int dh = 1; dh <= HALO; ++dh) {
                int dh2 = dh * dh;
                if (dh2 >= best2) break;
                int du = nearest_dw(smrow[sr - dh], w);
                if (du < 64) { int c = dh2 + du * du; if (c < best2) best2 = c; }
                int dd = nearest_dw(smrow[sr + dh], w);
                if (dd < 64) { int c = dh2 + dd * dd; if (c < best2) best2 = c; }
            }
            // exact iff best2 <= (HALO+1)^2: any true d^2 < best2 <= 16 needs
            // |dh|<=3 and |dw|<=3 — fully inside the examined window.
            if (best2 > (HALO + 1) * (HALO + 1)) best2 = fallback_ring_scan(img, gh, w);

            float dist = sqrtf((float)best2);   // integer-exact in fp32 (< 2^24)
            float x = xs[j];
            float p = 1.0f / (1.0f + expf(-x));
            acc += (double)(p * (dist - 1.0f));
        }
    }

    // wave(64) shuffle reduce, then cross-wave LDS reduce
#pragma unroll
    for (int off = 32; off > 0; off >>= 1) acc += __shfl_down(acc, off, 64);
    if (lane == 0) s1[wv] = acc;
    __syncthreads();

    if (bid != 0) {
        // Producer: publish partial with device-coherent store, then release flag.
        if (t == 0) {
            double a = 0.0;
#pragma unroll
            for (int i = 0; i < NW; ++i) a += s1[i];
            __hip_atomic_store(&partial[bid], a, __ATOMIC_RELAXED, __HIP_MEMORY_SCOPE_AGENT);
            __hip_atomic_store(&flags[bid], FLAG_BASE | (unsigned)bid,
                               __ATOMIC_RELEASE, __HIP_MEMORY_SCOPE_AGENT);
        }
        return;
    }

    // Consumer (block 0): keep own sum in a register, then gather everyone else's.
    double own = 0.0;
    if (t == 0) {
#pragma unroll
        for (int i = 0; i < NW; ++i) own += s1[i];
    }
    __syncthreads();   // orders own-read before s1 reuse below

    double a1 = 0.0;
    if (t >= 1 && t < NBLK) {          // threads 1..255 each own one producer
        unsigned want = FLAG_BASE | (unsigned)t;
        while (__hip_atomic_load(&flags[t], __ATOMIC_ACQUIRE, __HIP_MEMORY_SCOPE_AGENT) != want) {
            __builtin_amdgcn_s_sleep(1);
        }
        a1 = __hip_atomic_load(&partial[t], __ATOMIC_RELAXED, __HIP_MEMORY_SCOPE_AGENT);
    }
#pragma unroll
    for (int off = 32; off > 0; off >>= 1) a1 += __shfl_down(a1, off, 64);
    if (lane == 0) s1[wv] = a1;
    __syncthreads();
    if (t == 0) {
        double total = own;
#pragma unroll
        for (int i = 0; i < NW; ++i) total += s1[i];
        out[0] = (float)(1.0 + total / (double)N_TOTAL);
    }
}

extern "C" void kernel_launch(void* const* d_in, const int* in_sizes, int n_in,
                              void* d_out, int out_size, void* d_ws, size_t ws_size,
                              hipStream_t stream) {
    const float* logits = (const float*)d_in[0];
    const int* targets  = (const int*)d_in[1];
    float* out = (float*)d_out;
    // ws layout: partial doubles [NBLK] (2048 B), then u32 flags [NBLK] (1024 B).
    // Flags are matched against per-slot magic (FLAG_BASE|bid): the 0xAA
    // poison (or any stale/garbage word) can never alias a valid flag.
    double* partial = (double*)d_ws;
    unsigned int* flags = (unsigned int*)((char*)d_ws + (size_t)NBLK * sizeof(double));

    fused_edt_loss<<<NBLK, BLOCK, 0, stream>>>(logits, targets, partial, flags, out);
}